// Round 8
// baseline (391.859 us; speedup 1.0000x reference)
//
#include <hip/hip_runtime.h>

typedef __attribute__((ext_vector_type(8))) _Float16 half8;
typedef __attribute__((ext_vector_type(4))) _Float16 half4;
typedef __attribute__((ext_vector_type(4))) float f32x4;

// ---------- elementwise: fp32 -> fp16 ----------
__global__ __launch_bounds__(256) void conv4_k(const float4* __restrict__ in,
                                               half4* __restrict__ out){
  int i = blockIdx.x * 256 + threadIdx.x;
  float4 v = in[i];
  half4 h = { (_Float16)v.x, (_Float16)v.y, (_Float16)v.z, (_Float16)v.w };
  out[i] = h;
}

// ---------- mask dtype detection ----------
__global__ void mask_detect(const unsigned int* __restrict__ m, int* __restrict__ flag){
  if (threadIdx.x == 0 && blockIdx.x == 0){
    int ok = 1;
#pragma unroll
    for (int j = 0; j < 16; j++){
      unsigned v = m[j];
      if (v != 0u && v != 1u && v != 0x3f800000u) ok = 0;
    }
    *flag = ok;
  }
}

// ---------- row softmax over 2048 fp32 -> fp16 P ----------
__global__ __launch_bounds__(256) void softmax2048(const float* __restrict__ S,
                                                   _Float16* __restrict__ P){
  const long row = blockIdx.x;
  const float* s = S + row * 2048;
  _Float16* p = P + row * 2048;
  const int tid = threadIdx.x;
  float v[8];
  float m = -1e30f;
#pragma unroll
  for (int i = 0; i < 8; i++){ v[i] = s[tid + i * 256]; m = fmaxf(m, v[i]); }
#pragma unroll
  for (int o = 32; o; o >>= 1) m = fmaxf(m, __shfl_xor(m, o));
  __shared__ float rm[4], rs[4];
  if ((tid & 63) == 0) rm[tid >> 6] = m;
  __syncthreads();
  m = fmaxf(fmaxf(rm[0], rm[1]), fmaxf(rm[2], rm[3]));
  float sum = 0.f;
#pragma unroll
  for (int i = 0; i < 8; i++){ v[i] = __expf(v[i] - m); sum += v[i]; }
#pragma unroll
  for (int o = 32; o; o >>= 1) sum += __shfl_xor(sum, o);
  if ((tid & 63) == 0) rs[tid >> 6] = sum;
  __syncthreads();
  sum = rs[0] + rs[1] + rs[2] + rs[3];
  const float inv = 1.0f / sum;
#pragma unroll
  for (int i = 0; i < 8; i++) p[tid + i * 256] = (_Float16)(v[i] * inv);
}

// ---------- GEMM 256x256, 4-phase m201-style schedule ----------
// C(MxN) = A(MxK) @ B(NxK)^T, fp16 in / fp32 accum. BM=BN=256, BK=64,
// 512 threads = 8 waves (2Mx4N). LDS 2x64KB double buffer.
// Phase template (m201): {ds_read(this phase's operands) ; stage ; BAR ;
//   lgkmcnt(0)[compiler] ; setprio(1) MFMA setprio(0) ; BAR}
// Staging depth 1.5 tiles, counted vmcnt (T4, never 0 mid-loop):
//   tile t: ph0/ph1 stage chunks 2,3 of t+1 into nb;
//           ph3 stages chunks 0,1 of t+2 into cb (cb reads all done by
//           ph2's post-MFMA BAR), then vmcnt(4): certifies t+1 (oldest 4)
//           while t+2's 4 loads stay in flight.
// T2 swizzle (verified R7: conflicts 15.7M -> 0): 16B granule g at linear
//   g^(row&7); staging keeps linear LDS dest, pre-swizzles global source col;
//   ds_read applies same XOR. Rule 21: same involution both sides.
// EPI: 0 fp32 (+bias) | 1 fp32 masked (scores) | 2 fp16 (+bias)
//      5 fused KV: col<1024 -> K fp16 ; col>=1024 -> VT[b][col-1024][row&2047]
#define GLL(gp, ldsoff) \
  __builtin_amdgcn_global_load_lds((const __attribute__((address_space(1))) void*)(gp), \
                                   (__attribute__((address_space(3))) void*)&lds[ldsoff], 16, 0, 0)
#define BAR() asm volatile("s_barrier" ::: "memory")
#define VMCNT(n) asm volatile("s_waitcnt vmcnt(" #n ")" ::: "memory")

template<int EPI>
__global__ __launch_bounds__(512, 2)
void gemm256(const unsigned short* __restrict__ A, const unsigned short* __restrict__ B,
             int lda, int ldb, int K, const float* __restrict__ bias,
             const void* __restrict__ mask, const int* __restrict__ maskFlag,
             void* __restrict__ out0, void* __restrict__ out1, int ldc,
             long aBS, long bBS, long oBS, int maskBS)
{
  constexpr int BUFSZ = 32768;                  // elements: A 256x64 + B 256x64
  __shared__ short lds[2 * BUFSZ];              // 128 KB

  const int z = blockIdx.z;
  const long zA = (long)z * aBS, zB = (long)z * bBS;
  const int tid = threadIdx.x;
  const int lane = tid & 63, wid = tid >> 6;
  const int wr = wid >> 2, wc = wid & 3;
  const int fr = lane & 15, fk = lane >> 4;
  const int brow = blockIdx.x * 256, bcol = blockIdx.y * 256;

  f32x4 acc[8][4];
  const f32x4 fzero = {0.f, 0.f, 0.f, 0.f};
#pragma unroll
  for (int i = 0; i < 8; i++)
#pragma unroll
    for (int j = 0; j < 4; j++) acc[i][j] = fzero;

  // staging: thread tid -> LDS linear granule (srow, tid&7); source col swizzled
  const int srow = tid >> 3;
  const int scol = ((tid & 7) ^ (srow & 7)) * 8;
  const unsigned short* Ag = A + zA + (long)(brow + srow) * lda + scol;
  const unsigned short* Bg = B + zB + (long)(bcol + srow) * ldb + scol;

  // ds_read swizzled col offsets (elements), per lane:
  const int frs = fr & 7;
  const int c0 = ((0 * 4 + fk) ^ frs) * 8;      // kk=0
  const int c1 = ((1 * 4 + fk) ^ frs) * 8;      // kk=1
  const int aRow = wr * 8192 + fr * 64;         // + qm*4096 + mi*1024 + c{0,1}
  const int bRow = wc * 4096 + fr * 64;         // + ni*1024 + c{0,1}  (B base +16384)

  auto stage = [&](int nb, int c, long k1) {
    if (c < 2) {
      const unsigned short* g = Ag + (long)(c * 128) * lda + k1;
      GLL(g,                  nb + c * 8192 + tid * 8);
      GLL(g + (long)64 * lda, nb + c * 8192 + 4096 + tid * 8);
    } else {
      const unsigned short* g = Bg + (long)((c - 2) * 128) * ldb + k1;
      GLL(g,                  nb + 16384 + (c - 2) * 8192 + tid * 8);
      GLL(g + (long)64 * ldb, nb + 16384 + (c - 2) * 8192 + 4096 + tid * 8);
    }
  };

  half8 a[4][2], b[4][2];
  auto readA = [&](int cb, int qm) {
#pragma unroll
    for (int mi = 0; mi < 4; ++mi) {
      const int e = cb + aRow + qm * 4096 + mi * 1024;
      a[mi][0] = *(const half8*)&lds[e + c0];
      a[mi][1] = *(const half8*)&lds[e + c1];
    }
  };
  auto readB = [&](int cb, int n0) {
#pragma unroll
    for (int i = 0; i < 2; ++i) {
      const int ni = n0 + i;
      const int e = cb + 16384 + bRow + ni * 1024;
      b[ni][0] = *(const half8*)&lds[e + c0];
      b[ni][1] = *(const half8*)&lds[e + c1];
    }
  };
  auto mmaQ = [&](int qm, int n0) {
#pragma unroll
    for (int mi = 0; mi < 4; ++mi)
#pragma unroll
      for (int i = 0; i < 2; ++i) {
        const int ni = n0 + i;
        f32x4 c = acc[qm * 4 + mi][ni];
        c = __builtin_amdgcn_mfma_f32_16x16x32_f16(a[mi][0], b[ni][0], c, 0, 0, 0);
        c = __builtin_amdgcn_mfma_f32_16x16x32_f16(a[mi][1], b[ni][1], c, 0, 0, 0);
        acc[qm * 4 + mi][ni] = c;
      }
  };

  const int nt = K >> 6;                         // K >= 128 always here
  // prologue: tile0 fully + tile1 chunks 0,1 -> 12 loads; certify tile0 (oldest 8)
  for (int c = 0; c < 4; ++c) stage(0, c, 0);
  stage(BUFSZ, 0, 64);
  stage(BUFSZ, 1, 64);
  VMCNT(4);
  BAR();

  for (int t = 0; t < nt; ++t) {
    const int cb = (t & 1) ? BUFSZ : 0, nb = cb ^ BUFSZ;
    const long k1 = (long)(t + 1) << 6;
    const long k2 = (long)(t + 2) << 6;
    const bool pf1 = (t + 1 < nt), pf2 = (t + 2 < nt);
    // ph0: (qm0, n0-1) — reads BEFORE barrier (hide under arrival spread)
    readA(cb, 0); readB(cb, 0);
    if (pf1) stage(nb, 2, k1);
    BAR();
    __builtin_amdgcn_s_setprio(1); mmaQ(0, 0); __builtin_amdgcn_s_setprio(0);
    BAR();
    // ph1: (qm0, n2-3)
    readB(cb, 2);
    if (pf1) stage(nb, 3, k1);
    BAR();
    __builtin_amdgcn_s_setprio(1); mmaQ(0, 2); __builtin_amdgcn_s_setprio(0);
    BAR();
    // ph2: (qm1, n2-3) — last cb ds_reads
    readA(cb, 1);
    BAR();
    __builtin_amdgcn_s_setprio(1); mmaQ(1, 2); __builtin_amdgcn_s_setprio(0);
    BAR();
    // ph3: (qm1, n0-1) — regs already resident; stage t+2 chunks 0,1 into cb
    // (all cb reads completed by ph2's post-MFMA BAR); counted wait certifies t+1
    if (pf2) { stage(cb, 0, k2); stage(cb, 1, k2); VMCNT(4); }
    else     { VMCNT(0); }
    BAR();
    __builtin_amdgcn_s_setprio(1); mmaQ(1, 0); __builtin_amdgcn_s_setprio(0);
    BAR();
  }

  // epilogue: C/D frag layout col=lane&15, row=(lane>>4)*4+r  [m89-verified]
  const long zO = (long)z * oBS;
  int mflag = 0;
  if constexpr (EPI == 1) mflag = *maskFlag;
#pragma unroll
  for (int mi = 0; mi < 8; ++mi) {
#pragma unroll
    for (int ni = 0; ni < 4; ++ni) {
      const int col = bcol + wc * 64 + ni * 16 + fr;
      float bv = 0.f;
      if constexpr (EPI != 1) { if (bias) bv = bias[col]; }
      bool msk = false;
      if constexpr (EPI == 1) {
        msk = mflag ? (((const int*)mask)[(long)z * maskBS + col] != 0)
                    : (((const unsigned char*)mask)[(long)z * maskBS + col] != 0);
      }
#pragma unroll
      for (int r = 0; r < 4; ++r) {
        const int row = brow + wr * 128 + mi * 16 + fk * 4 + r;
        float v = acc[mi][ni][r] + bv;
        if constexpr (EPI == 0) {
          ((float*)out0)[zO + (long)row * ldc + col] = v;
        } else if constexpr (EPI == 1) {
          ((float*)out0)[zO + (long)row * ldc + col] = msk ? -1e30f : v;
        } else if constexpr (EPI == 2) {
          ((_Float16*)out0)[zO + (long)row * ldc + col] = (_Float16)v;
        } else {                      // EPI==5: fused K | V^T
          if (col < 1024) {
            ((_Float16*)out0)[(long)row * 1024 + col] = (_Float16)v;
          } else {
            const int bb = row >> 11, tt = row & 2047;
            ((_Float16*)out1)[(long)bb * 2048 * 1024 + (long)(col - 1024) * 2048 + tt] = (_Float16)v;
          }
        }
      }
    }
  }
}

extern "C" void kernel_launch(void* const* d_in, const int* in_sizes, int n_in,
                              void* d_out, int out_size, void* d_ws, size_t ws_size,
                              hipStream_t stream)
{
  (void)in_sizes; (void)n_in; (void)out_size; (void)ws_size;
  const float* query = (const float*)d_in[0];   // (4,2048,1024)
  const float* key   = (const float*)d_in[1];   // (4,2048,1024)
  const void*  kmask = d_in[2];                 // (4,2048) bool -> dtype detected on device
  const float* Wq    = (const float*)d_in[3];   // (1024,1024)
  const float* bq    = (const float*)d_in[4];
  const float* Wk    = (const float*)d_in[5];   // (2048,1024)
  const float* bk    = (const float*)d_in[6];
  const float* Wfc   = (const float*)d_in[7];   // (1024,1024)
  const float* bfc   = (const float*)d_in[8];
  float* out = (float*)d_out;

  char* ws = (char*)d_ws;
  size_t o = 0;
  auto take = [&](size_t bytes)->char*{
    char* p = ws + o;
    o += (bytes + 255) & ~(size_t)255;
    return p;
  };
  const size_t SZ_H = (size_t)8192 * 1024 * 2;      // 16.78 MB (8192x1024 fp16)

  int* maskFlag           = (int*)take(256);
  unsigned short* query_h = (unsigned short*)take(SZ_H);
  unsigned short* key_h   = (unsigned short*)take(SZ_H);
  unsigned short* Wq_h    = (unsigned short*)take((size_t)1024 * 1024 * 2);
  unsigned short* Wk_h    = (unsigned short*)take((size_t)2048 * 1024 * 2);
  unsigned short* Wfc_h   = (unsigned short*)take((size_t)1024 * 1024 * 2);
  unsigned short* Q       = (unsigned short*)take(SZ_H);
  unsigned short* K       = (unsigned short*)take(SZ_H);
  unsigned short* VT      = (unsigned short*)take(SZ_H);
  unsigned short* O       = (unsigned short*)take(SZ_H);
  float*          S       = (float*)take((size_t)8192 * 2048 * 4);   // 67.1 MB
  unsigned short* P       = (unsigned short*)take((size_t)8192 * 2048 * 2); // 33.6 MB

  mask_detect<<<1, 64, 0, stream>>>((const unsigned int*)kmask, maskFlag);

  conv4_k<<<8192, 256, 0, stream>>>((const float4*)query, (half4*)query_h);
  conv4_k<<<8192, 256, 0, stream>>>((const float4*)key,   (half4*)key_h);
  conv4_k<<<1024, 256, 0, stream>>>((const float4*)Wq,    (half4*)Wq_h);
  conv4_k<<<2048, 256, 0, stream>>>((const float4*)Wk,    (half4*)Wk_h);
  conv4_k<<<1024, 256, 0, stream>>>((const float4*)Wfc,   (half4*)Wfc_h);

  // fused K|V: c = key @ Wk^T + bk  (8192x2048, K=1024); cols<1024 -> K, >=1024 -> VT
  gemm256<5><<<dim3(32, 8, 1), 512, 0, stream>>>(
      key_h, Wk_h, 1024, 1024, 1024,
      bk, nullptr, nullptr, K, VT, 1024, 0, 0, 0, 0);

  // Q = query @ Wq^T + bq   (8192x1024, K=1024) -> fp16
  gemm256<2><<<dim3(32, 4, 1), 512, 0, stream>>>(
      query_h, Wq_h, 1024, 1024, 1024,
      bq, nullptr, nullptr, Q, nullptr, 1024, 0, 0, 0, 0);

  // scores: per batch S = Q @ K^T, masked  (2048x2048, K=1024) -> fp32
  gemm256<1><<<dim3(8, 8, 4), 512, 0, stream>>>(
      Q, K, 1024, 1024, 1024,
      nullptr, kmask, maskFlag, S, nullptr, 2048,
      (long)2048 * 1024, (long)2048 * 1024, (long)2048 * 2048, 2048);

  softmax2048<<<8192, 256, 0, stream>>>(S, (_Float16*)P);

  // O = P @ V  (per batch 2048x1024, K=2048; B = VT) -> fp16
  gemm256<2><<<dim3(8, 4, 4), 512, 0, stream>>>(
      P, VT, 2048, 2048, 2048,
      nullptr, nullptr, nullptr, O, nullptr, 1024,
      (long)2048 * 2048, (long)1024 * 2048, (long)2048 * 1024, 0);

  // out = O @ Wfc^T + bfc  (8192x1024, K=1024) -> fp32
  gemm256<0><<<dim3(32, 4, 1), 512, 0, stream>>>(
      O, Wfc_h, 1024, 1024, 1024,
      bfc, nullptr, nullptr, out, nullptr, 1024, 0, 0, 0, 0);
}